// Round 1
// 596.959 us; speedup vs baseline: 1.0319x; 1.0319x over previous
//
#include <hip/hip_runtime.h>
#include <cstdint>

#define B_   32
#define T1_  2048
#define T2_  512

typedef __attribute__((ext_vector_type(8))) short short8;   // 8 x bf16 (4 VGPRs)
typedef __attribute__((ext_vector_type(4))) float f32x4;

__device__ __forceinline__ unsigned short f2bf(float f) {
    union { float f; unsigned u; } x; x.f = f;
    unsigned r = x.u + 0x7fffu + ((x.u >> 16) & 1u);   // RNE
    return (unsigned short)(r >> 16);
}
__device__ __forceinline__ float bf2f(unsigned short u) {
    union { unsigned u; float f; } x; x.u = ((unsigned)u) << 16;
    return x.f;
}

__device__ __forceinline__ void async16(const unsigned short* g, unsigned short* l) {
    __builtin_amdgcn_global_load_lds(
        (const __attribute__((address_space(1))) unsigned int*)g,
        (__attribute__((address_space(3))) unsigned int*)l, 16, 0, 0);
}

// ---------------------------------------------------------------------------
// prep: (a) transpose-cast keys -> keysT [32][514][512] bf16 (rows t=-1,T zero)
//       (b) transpose-cast queries -> queriesT [32][2050][128] bf16
//       (c) all 5 weight casts into one contiguous bf16 region.
// Coarsened 4x along t vs previous round: blocks [0,2048) keys (4 tiles each),
// [2048,4096) queries (4 tiles each), [4096,5120) weights.
// ---------------------------------------------------------------------------
__global__ __launch_bounds__(256) void prep_kernel(
    const float* __restrict__ queries, const float* __restrict__ keys,
    const float* __restrict__ kW1, const float* __restrict__ kW2,
    const float* __restrict__ qW1, const float* __restrict__ qW2,
    const float* __restrict__ qW3,
    unsigned short* __restrict__ keysT, unsigned short* __restrict__ queriesT,
    unsigned short* __restrict__ Wdst)
{
    __shared__ float tile[32][33];
    const int blk = blockIdx.x, tid = threadIdx.x;
    if (blk < 4096) {
        const float* X; unsigned short* Y; int C, Cp, T, ntx, ty, tx0, b;
        if (blk < 2048) {
            X = keys; Y = keysT; C = 512; Cp = 512; T = 512; ntx = 16;
            b = blk >> 6; int rem = blk & 63; ty = rem >> 2; tx0 = (rem & 3) * 4;
        } else {
            int f = blk - 2048;
            X = queries; Y = queriesT; C = 100; Cp = 128; T = 2048; ntx = 64;
            b = f >> 6; int rem = f & 63; ty = rem & 3; tx0 = (rem >> 2) * 4;
        }
        const int c0 = ty * 32;
        const int cl = tid >> 5, tl = tid & 31;
        for (int tx = tx0; tx < tx0 + 4; ++tx) {
            const int t0 = tx * 32;
            __syncthreads();
#pragma unroll
            for (int i = 0; i < 4; ++i) {
                int c = c0 + cl + i * 8;
                float v = (c < C) ? X[((size_t)b * C + c) * T + t0 + tl] : 0.f;
                tile[cl + i * 8][tl] = v;
            }
            __syncthreads();
#pragma unroll
            for (int i = 0; i < 4; ++i) {
                int tw = cl + i * 8, cw = tl;
                Y[((size_t)b * (T + 2) + t0 + tw + 1) * Cp + c0 + cw] = f2bf(tile[cw][tw]);
            }
            if (tid < 32) {
                if (tx == 0)       Y[((size_t)b * (T + 2)) * Cp + c0 + tid] = 0;
                if (tx == ntx - 1) Y[((size_t)b * (T + 2) + T + 1) * Cp + c0 + tid] = 0;
            }
        }
    } else {
        size_t base = (size_t)(blk - 4096) * 2048 + (size_t)tid * 8;
#pragma unroll
        for (int j = 0; j < 8; ++j) {
            size_t idx = base + j;
            float v = 0.f;
            if (idx < 1572864) {                  // Wk1s [3][1024][512]
                int dk = (int)(idx / 524288); int rem = (int)(idx % 524288);
                int m = rem >> 9, ci = rem & 511;
                v = kW1[((size_t)m * 512 + ci) * 3 + dk];
            } else if (idx < 1703936) {           // Wk2 [128][1024]
                int r = (int)(idx - 1572864); int m = r >> 10, c = r & 1023;
                if (m < 100) v = kW2[(size_t)m * 1024 + c];
            } else if (idx < 1802240) {           // Wq1s [3][256][128]
                int r = (int)(idx - 1703936); int dk = r / 32768, rem = r % 32768;
                int m = rem >> 7, ci = rem & 127;
                if (m < 200 && ci < 100) v = qW1[((size_t)m * 100 + ci) * 3 + dk];
            } else if (idx < 1835008) {           // Wq2 [128][256]
                int r = (int)(idx - 1802240); int m = r >> 8, c = r & 255;
                if (m < 100 && c < 200) v = qW2[(size_t)m * 200 + c];
            } else if (idx < 1851392) {           // Wq3 [128][128]
                int r = (int)(idx - 1835008); int m = r >> 7, c = r & 127;
                if (m < 100 && c < 100) v = qW3[(size_t)m * 100 + c];
            } else {
                continue;
            }
            Wdst[idx] = f2bf(v);
        }
    }
}

// ---------------------------------------------------------------------------
// Paired bf16 MFMA conv-GEMM, BK=64 (m97-verified config): 32 MFMAs per
// barrier pair, half the barrier-drain stalls of BK=32. LDS tiles are
// [128][64] bf16; a row-major read at 128 B row stride is a 16-way bank
// conflict, so the 16B slots are XOR-swizzled (slot ^= row&7) with the
// inverse swizzle applied to the per-lane GLOBAL source of global_load_lds
// (LDS dest stays linear — both-sides-or-neither rule). KW=3: conv as 3
// accumulating GEMM passes over shifted row windows. Writes Y transposed
// as [b][N][Mpad] bf16 via LDS-staged epilogue; optional fused row-norms.
// Two independent GEMMs per launch (flat-grid split).
// ---------------------------------------------------------------------------
struct GArgs {
    const unsigned short* A;
    const unsigned short* Bm;
    const float* bias;
    unsigned short* Y;
    float* nrm;
    int Ck, N, Mpad, nx, relu, norm, Cout;
};

template<int KW>
__global__ __launch_bounds__(256) void gemm_pair(GArgs g0, GArgs g1, int n0)
{
    __shared__ __align__(16) unsigned char smem[36352];
    unsigned short* Al = (unsigned short*)smem;           // [128][64] swizzled
    unsigned short* Bl = Al + 8192;                       // [128][64] swizzled
    unsigned short* Ct = (unsigned short*)smem;           // [128][136] epilogue
    float* biasS = (float*)(smem + 34816);                // [128]
    float* normS = (float*)(smem + 35328);                // [2][128]

    const bool first = (blockIdx.x < (unsigned)n0);
    const GArgs g = first ? g0 : g1;
    const int idx = first ? blockIdx.x : (blockIdx.x - n0);
    const int ny = g.Mpad >> 7;
    const int per_b = g.nx * ny;
    const int b = idx / per_b; const int rem = idx - b * per_b;
    const int y = rem / g.nx, x = rem - y * g.nx;
    const int co0 = y * 128, t0 = x * 128;

    const int tid = threadIdx.x;
    const int wave = tid >> 6, lane = tid & 63;
    const int lm = lane & 15, kg = lane >> 4;
    const int mbase = (wave >> 1) * 64, nbase = (wave & 1) * 64;

    if (tid < 128) biasS[tid] = (co0 + tid < g.Cout) ? g.bias[co0 + tid] : 0.f;

    // staging lane decomposition: 8 rows x 8 16B-slots per wave-call
    const int r7 = lane >> 3;            // relative row 0..7
    const int s7 = lane & 7;             // physical 16B slot 0..7
    const int swz = ((s7 ^ r7) * 8);     // inverse-swizzled global col (elems)
    const int Ck = g.Ck;

    f32x4 acc[4][4];
#pragma unroll
    for (int mi = 0; mi < 4; ++mi)
#pragma unroll
        for (int ni = 0; ni < 4; ++ni) acc[mi][ni] = (f32x4){0.f, 0.f, 0.f, 0.f};

#pragma unroll 1
    for (int dk = 0; dk < KW; ++dk) {
        const unsigned short* Ad = g.A + ((size_t)dk * g.Mpad + co0) * Ck;
        const unsigned short* Bd = g.Bm +
            ((size_t)b * (g.N + (KW == 3 ? 2 : 0)) + t0 + dk) * Ck;
        for (int kk = 0; kk < Ck; kk += 64) {
            __syncthreads();
#pragma unroll
            for (int i = 0; i < 4; ++i) {
                int R0 = wave * 32 + i * 8;   // wave-uniform LDS base row
                async16(Ad + (size_t)(R0 + r7) * Ck + kk + swz, Al + R0 * 64);
                async16(Bd + (size_t)(R0 + r7) * Ck + kk + swz, Bl + R0 * 64);
            }
            __syncthreads();
#pragma unroll
            for (int kk2 = 0; kk2 < 2; ++kk2) {
                short8 av[4], bv[4];
#pragma unroll
                for (int mi = 0; mi < 4; ++mi) {
                    int row = mbase + mi * 16 + lm;
                    av[mi] = *(const short8*)(Al + row * 64 +
                                              (((kk2 * 4 + kg) ^ (lm & 7)) * 8));
                }
#pragma unroll
                for (int ni = 0; ni < 4; ++ni) {
                    int row = nbase + ni * 16 + lm;
                    bv[ni] = *(const short8*)(Bl + row * 64 +
                                              (((kk2 * 4 + kg) ^ (lm & 7)) * 8));
                }
#pragma unroll
                for (int mi = 0; mi < 4; ++mi)
#pragma unroll
                    for (int ni = 0; ni < 4; ++ni)
                        acc[mi][ni] = __builtin_amdgcn_mfma_f32_16x16x32_bf16(
                            av[mi], bv[ni], acc[mi][ni], 0, 0, 0);
            }
        }
    }
    __syncthreads();

    // epilogue: bias(+relu), stage transposed bf16 tile, fused row-norms
    float sq[4] = {0.f, 0.f, 0.f, 0.f};
#pragma unroll
    for (int mi = 0; mi < 4; ++mi)
#pragma unroll
        for (int ni = 0; ni < 4; ++ni)
#pragma unroll
            for (int r = 0; r < 4; ++r) {
                int co_l = mbase + mi * 16 + kg * 4 + r;
                int t_l  = nbase + ni * 16 + lm;
                float v = acc[mi][ni][r] + biasS[co_l];
                if (g.relu) v = fmaxf(v, 0.f);
                Ct[t_l * 136 + co_l] = f2bf(v);
                sq[ni] += v * v;
            }
    if (g.norm) {
#pragma unroll
        for (int ni = 0; ni < 4; ++ni) {
            float s = sq[ni];
            s += __shfl_xor(s, 16, 64);
            s += __shfl_xor(s, 32, 64);
            if (kg == 0) normS[(wave >> 1) * 128 + nbase + ni * 16 + lm] = s;
        }
    }
    __syncthreads();
    unsigned short* Yb = g.Y + ((size_t)b * g.N + t0) * g.Mpad + co0;
    int c0 = (tid & 15) * 8;
#pragma unroll
    for (int p = 0; p < 8; ++p) {
        int r = (tid >> 4) + p * 16;
        *(uint4*)(Yb + (size_t)r * g.Mpad + c0) = *(const uint4*)(Ct + r * 136 + c0);
    }
    if (g.norm && tid < 128)
        g.nrm[(size_t)b * g.N + t0 + tid] = normS[tid] + normS[128 + tid];
}

// ---------------------------------------------------------------------------
// MFMA attention (unchanged — passed). Block = (b, 32 q-rows) x all 512 cols;
// wave w owns cols [128w,128w+128); frags straight from L2.
// ---------------------------------------------------------------------------
__global__ __launch_bounds__(256) void attn_mfma(
    const unsigned short* __restrict__ q,   // [B*T1][128] bf16
    const unsigned short* __restrict__ k,   // [B*T2][128] bf16
    const float* __restrict__ q2,           // [B*T1]
    const float* __restrict__ k2,           // [B*T2]
    const unsigned char* __restrict__ mask, // [B*T2]
    const float* __restrict__ prior,        // [B,T1,T2]
    float* __restrict__ out_attn, float* __restrict__ out_logp)
{
    __shared__ float redM[4][32], redS[4][32];
    __shared__ float rowA[32], rowB[32];

    const int b = blockIdx.y, t0 = blockIdx.x * 32;
    const int tid = threadIdx.x, wave = tid >> 6, lane = tid & 63;
    const int lm = lane & 15, quad = lane >> 4;
    const float NEG_INF = -__builtin_huge_valf();

    const unsigned short* qb = q + ((size_t)b * T1_ + t0) * 128;
    short8 af[2][4];
#pragma unroll
    for (int mi = 0; mi < 2; ++mi)
#pragma unroll
        for (int kb = 0; kb < 4; ++kb)
            af[mi][kb] = *(const short8*)(qb + (size_t)(mi * 16 + lm) * 128 + kb * 32 + quad * 8);

    f32x4 acc[2][8];
#pragma unroll
    for (int mi = 0; mi < 2; ++mi)
#pragma unroll
        for (int nf = 0; nf < 8; ++nf) acc[mi][nf] = (f32x4){0.f, 0.f, 0.f, 0.f};

    const unsigned short* kp = k + ((size_t)b * T2_ + wave * 128) * 128;
#pragma unroll
    for (int nf = 0; nf < 8; ++nf) {
        short8 bfr[4];
#pragma unroll
        for (int kb = 0; kb < 4; ++kb)
            bfr[kb] = *(const short8*)(kp + (size_t)(nf * 16 + lm) * 128 + kb * 32 + quad * 8);
#pragma unroll
        for (int mi = 0; mi < 2; ++mi)
#pragma unroll
            for (int kb = 0; kb < 4; ++kb)
                acc[mi][nf] = __builtin_amdgcn_mfma_f32_16x16x32_bf16(
                    af[mi][kb], bfr[kb], acc[mi][nf], 0, 0, 0);
    }

    float k2v[8];
    unsigned char mk[8];
#pragma unroll
    for (int nf = 0; nf < 8; ++nf) {
        int col = wave * 128 + nf * 16 + lm;
        k2v[nf] = k2[b * T2_ + col];
        mk[nf]  = mask[b * T2_ + col];
    }
    float q2v[2][4];
#pragma unroll
    for (int mi = 0; mi < 2; ++mi)
#pragma unroll
        for (int r = 0; r < 4; ++r)
            q2v[mi][r] = q2[b * T1_ + t0 + mi * 16 + quad * 4 + r];
#pragma unroll
    for (int mi = 0; mi < 2; ++mi)
#pragma unroll
        for (int nf = 0; nf < 8; ++nf)
#pragma unroll
            for (int r = 0; r < 4; ++r)
                acc[mi][nf][r] = 1e-3f * acc[mi][nf][r] - 5e-4f * (q2v[mi][r] + k2v[nf]);

#pragma unroll
    for (int mi = 0; mi < 2; ++mi)
#pragma unroll
        for (int r = 0; r < 4; ++r) {
            float m = NEG_INF;
#pragma unroll
            for (int nf = 0; nf < 8; ++nf) m = fmaxf(m, acc[mi][nf][r]);
#pragma unroll
            for (int d = 1; d <= 8; d <<= 1) m = fmaxf(m, __shfl_xor(m, d, 64));
            float s = 0.f;
#pragma unroll
            for (int nf = 0; nf < 8; ++nf) s += __expf(acc[mi][nf][r] - m);
#pragma unroll
            for (int d = 1; d <= 8; d <<= 1) s += __shfl_xor(s, d, 64);
            if (lm == 0) {
                redM[wave][mi * 16 + quad * 4 + r] = m;
                redS[wave][mi * 16 + quad * 4 + r] = s;
            }
        }
    __syncthreads();
    if (tid < 32) {
        float m = redM[0][tid];
        m = fmaxf(m, redM[1][tid]); m = fmaxf(m, redM[2][tid]); m = fmaxf(m, redM[3][tid]);
        float s = 0.f;
#pragma unroll
        for (int w = 0; w < 4; ++w) s += redS[w][tid] * __expf(redM[w][tid] - m);
        rowA[tid] = m + __logf(s);   // L1
    }
    __syncthreads();
    float L1[2][4];
#pragma unroll
    for (int mi = 0; mi < 2; ++mi)
#pragma unroll
        for (int r = 0; r < 4; ++r) L1[mi][r] = rowA[mi * 16 + quad * 4 + r];

    const size_t base = ((size_t)b * T1_ + t0) * T2_;
#pragma unroll
    for (int mi = 0; mi < 2; ++mi)
#pragma unroll
        for (int r = 0; r < 4; ++r) {
            size_t rowoff = base + (size_t)(mi * 16 + quad * 4 + r) * T2_;
#pragma unroll
            for (int nf = 0; nf < 8; ++nf) {
                int col = wave * 128 + nf * 16 + lm;
                float pv = prior[rowoff + col];
                float t = acc[mi][nf][r] + __logf(pv + 1e-8f);
                out_logp[rowoff + col] = t - L1[mi][r];
                acc[mi][nf][r] = mk[nf] ? NEG_INF : t;
            }
        }

#pragma unroll
    for (int mi = 0; mi < 2; ++mi)
#pragma unroll
        for (int r = 0; r < 4; ++r) {
            float m = NEG_INF;
#pragma unroll
            for (int nf = 0; nf < 8; ++nf) m = fmaxf(m, acc[mi][nf][r]);
#pragma unroll
            for (int d = 1; d <= 8; d <<= 1) m = fmaxf(m, __shfl_xor(m, d, 64));
            float s = 0.f;
#pragma unroll
            for (int nf = 0; nf < 8; ++nf) s += __expf(acc[mi][nf][r] - m);
#pragma unroll
            for (int d = 1; d <= 8; d <<= 1) s += __shfl_xor(s, d, 64);
            if (lm == 0) {
                redM[wave][mi * 16 + quad * 4 + r] = m;
                redS[wave][mi * 16 + quad * 4 + r] = s;
            }
        }
    __syncthreads();
    if (tid < 32) {
        float m = redM[0][tid];
        m = fmaxf(m, redM[1][tid]); m = fmaxf(m, redM[2][tid]); m = fmaxf(m, redM[3][tid]);
        float s = 0.f;
#pragma unroll
        for (int w = 0; w < 4; ++w) s += redS[w][tid] * __expf(redM[w][tid] - m);
        rowA[tid] = m;
        rowB[tid] = 1.0f / s;
    }
    __syncthreads();

#pragma unroll
    for (int mi = 0; mi < 2; ++mi)
#pragma unroll
        for (int r = 0; r < 4; ++r) {
            int rl = mi * 16 + quad * 4 + r;
            float m2 = rowA[rl], is2 = rowB[rl];
            size_t rowoff = base + (size_t)rl * T2_;
#pragma unroll
            for (int nf = 0; nf < 8; ++nf) {
                int col = wave * 128 + nf * 16 + lm;
                out_attn[rowoff + col] = __expf(acc[mi][nf][r] - m2) * is2;
            }
        }
}

extern "C" void kernel_launch(void* const* d_in, const int* in_sizes, int n_in,
                              void* d_out, int out_size, void* d_ws, size_t ws_size,
                              hipStream_t stream)
{
    const float* queries = (const float*)d_in[0];
    const float* keys    = (const float*)d_in[1];
    const unsigned char* mask = (const unsigned char*)d_in[3];
    const float* prior   = (const float*)d_in[4];
    const float* kW1 = (const float*)d_in[5];
    const float* kb1 = (const float*)d_in[6];
    const float* kW2 = (const float*)d_in[7];
    const float* kb2 = (const float*)d_in[8];
    const float* qW1 = (const float*)d_in[9];
    const float* qb1 = (const float*)d_in[10];
    const float* qW2 = (const float*)d_in[11];
    const float* qb2 = (const float*)d_in[12];
    const float* qW3 = (const float*)d_in[13];
    const float* qb3 = (const float*)d_in[14];

    // workspace (ushort units), ~142.5 MB total:
    unsigned short* ws = (unsigned short*)d_ws;
    unsigned short* keysT    = ws;                       //  32*514*512  = 8,421,376
    unsigned short* queriesT = ws + 8421376;             //  32*2050*128 = 8,396,800
    unsigned short* Bmat2    = ws + 16818176;            //  [32][512][1024]
    unsigned short* Bmat4    = ws + 33595392;            //  [32][2048][256]
    unsigned short* Bmat5    = ws + 50372608;            //  [32][2048][128]
    unsigned short* q_att    = ws + 58761216;            //  [32][2048][128]
    unsigned short* k_att    = ws + 67149824;            //  [32][512][128]
    unsigned short* Wdst     = ws + 69246976;            //  1,851,392 (5 regions)
    unsigned short* Wk1s = Wdst;                         //  [3][1024][512]
    unsigned short* Wk2  = Wdst + 1572864;               //  [128][1024]
    unsigned short* Wq1s = Wdst + 1703936;               //  [3][256][128]
    unsigned short* Wq2  = Wdst + 1802240;               //  [128][256]
    unsigned short* Wq3  = Wdst + 1835008;               //  [128][128]
    float* q2f = (float*)(ws + 71098368);                //  [65536] f32
    float* k2f = q2f + 65536;                            //  [16384] f32

    float* out_attn = (float*)d_out;
    float* out_logp = (float*)d_out + (size_t)B_ * T1_ * T2_;

    dim3 blk(256);
    prep_kernel<<<dim3(5120), blk, 0, stream>>>(queries, keys, kW1, kW2, qW1, qW2, qW3,
                                                keysT, queriesT, Wdst);

    GArgs a_key1 = {Wk1s, keysT,    kb1, Bmat2, nullptr, 512,  512, 1024,  4, 1, 0, 1024};
    GArgs a_q1   = {Wq1s, queriesT, qb1, Bmat4, nullptr, 128, 2048,  256, 16, 1, 0,  200};
    gemm_pair<3><<<dim3(2048), blk, 0, stream>>>(a_key1, a_q1, 1024);

    GArgs a_key2 = {Wk2, Bmat2, kb2, k_att, k2f,     1024,  512, 128,  4, 0, 1, 100};
    GArgs a_q2   = {Wq2, Bmat4, qb2, Bmat5, nullptr,  256, 2048, 128, 16, 1, 0, 100};
    gemm_pair<1><<<dim3(640), blk, 0, stream>>>(a_key2, a_q2, 128);

    GArgs a_q3   = {Wq3, Bmat5, qb3, q_att, q2f, 128, 2048, 128, 16, 0, 1, 100};
    gemm_pair<1><<<dim3(512), blk, 0, stream>>>(a_q3, a_q3, 512);

    attn_mfma<<<dim3(T1_ / 32, B_), blk, 0, stream>>>(q_att, k_att, q2f, k2f, mask, prior,
                                                      out_attn, out_logp);

    (void)in_sizes; (void)n_in; (void)out_size; (void)ws_size;
}

// Round 2
// 591.318 us; speedup vs baseline: 1.0417x; 1.0095x over previous
//
#include <hip/hip_runtime.h>
#include <cstdint>

#define B_   32
#define T1_  2048
#define T2_  512

typedef __attribute__((ext_vector_type(8))) short short8;   // 8 x bf16 (4 VGPRs)
typedef __attribute__((ext_vector_type(4))) float f32x4;

__device__ __forceinline__ unsigned short f2bf(float f) {
    union { float f; unsigned u; } x; x.f = f;
    unsigned r = x.u + 0x7fffu + ((x.u >> 16) & 1u);   // RNE
    return (unsigned short)(r >> 16);
}

__device__ __forceinline__ void async16(const unsigned short* g, unsigned short* l) {
    __builtin_amdgcn_global_load_lds(
        (const __attribute__((address_space(1))) unsigned int*)g,
        (__attribute__((address_space(3))) unsigned int*)l, 16, 0, 0);
}

// ---------------------------------------------------------------------------
// prep: (a) transpose-cast keys -> keysT [32][514][512] bf16 (rows t=-1,T zero)
//       (b) transpose-cast queries -> queriesT [32][2050][128] bf16
//       (c) all 5 weight casts into one contiguous bf16 region.
// Blocks: [0,2048) keys (4 tiles each), [2048,4096) queries, [4096,5120) weights.
// ---------------------------------------------------------------------------
__global__ __launch_bounds__(256) void prep_kernel(
    const float* __restrict__ queries, const float* __restrict__ keys,
    const float* __restrict__ kW1, const float* __restrict__ kW2,
    const float* __restrict__ qW1, const float* __restrict__ qW2,
    const float* __restrict__ qW3,
    unsigned short* __restrict__ keysT, unsigned short* __restrict__ queriesT,
    unsigned short* __restrict__ Wdst)
{
    __shared__ float tile[32][33];
    const int blk = blockIdx.x, tid = threadIdx.x;
    if (blk < 4096) {
        const float* X; unsigned short* Y; int C, Cp, T, ntx, ty, tx0, b;
        if (blk < 2048) {
            X = keys; Y = keysT; C = 512; Cp = 512; T = 512; ntx = 16;
            b = blk >> 6; int rem = blk & 63; ty = rem >> 2; tx0 = (rem & 3) * 4;
        } else {
            int f = blk - 2048;
            X = queries; Y = queriesT; C = 100; Cp = 128; T = 2048; ntx = 64;
            b = f >> 6; int rem = f & 63; ty = rem & 3; tx0 = (rem >> 2) * 4;
        }
        const int c0 = ty * 32;
        const int cl = tid >> 5, tl = tid & 31;
        for (int tx = tx0; tx < tx0 + 4; ++tx) {
            const int t0 = tx * 32;
            __syncthreads();
#pragma unroll
            for (int i = 0; i < 4; ++i) {
                int c = c0 + cl + i * 8;
                float v = (c < C) ? X[((size_t)b * C + c) * T + t0 + tl] : 0.f;
                tile[cl + i * 8][tl] = v;
            }
            __syncthreads();
#pragma unroll
            for (int i = 0; i < 4; ++i) {
                int tw = cl + i * 8, cw = tl;
                Y[((size_t)b * (T + 2) + t0 + tw + 1) * Cp + c0 + cw] = f2bf(tile[cw][tw]);
            }
            if (tid < 32) {
                if (tx == 0)       Y[((size_t)b * (T + 2)) * Cp + c0 + tid] = 0;
                if (tx == ntx - 1) Y[((size_t)b * (T + 2) + T + 1) * Cp + c0 + tid] = 0;
            }
        }
    } else {
        size_t base = (size_t)(blk - 4096) * 2048 + (size_t)tid * 8;
#pragma unroll
        for (int j = 0; j < 8; ++j) {
            size_t idx = base + j;
            float v = 0.f;
            if (idx < 1572864) {                  // Wk1s [3][1024][512]
                int dk = (int)(idx / 524288); int rem = (int)(idx % 524288);
                int m = rem >> 9, ci = rem & 511;
                v = kW1[((size_t)m * 512 + ci) * 3 + dk];
            } else if (idx < 1703936) {           // Wk2 [128][1024]
                int r = (int)(idx - 1572864); int m = r >> 10, c = r & 1023;
                if (m < 100) v = kW2[(size_t)m * 1024 + c];
            } else if (idx < 1802240) {           // Wq1s [3][256][128]
                int r = (int)(idx - 1703936); int dk = r / 32768, rem = r % 32768;
                int m = rem >> 7, ci = rem & 127;
                if (m < 200 && ci < 100) v = qW1[((size_t)m * 100 + ci) * 3 + dk];
            } else if (idx < 1835008) {           // Wq2 [128][256]
                int r = (int)(idx - 1802240); int m = r >> 8, c = r & 255;
                if (m < 100 && c < 200) v = qW2[(size_t)m * 200 + c];
            } else if (idx < 1851392) {           // Wq3 [128][128]
                int r = (int)(idx - 1835008); int m = r >> 7, c = r & 127;
                if (m < 100 && c < 100) v = qW3[(size_t)m * 100 + c];
            } else {
                continue;
            }
            Wdst[idx] = f2bf(v);
        }
    }
}

// ---------------------------------------------------------------------------
// Paired bf16 MFMA conv-GEMM, BK=64, DOUBLE-BUFFERED single-barrier pipeline:
// stage(s+1) is issued BEFORE compute(s); the one __syncthreads() per step
// (compiler emits vmcnt(0) drain there) lands after the MFMAs, so the global
// load latency hides under compute (T3/T4 minimum recipe). LDS tiles are
// [128][64] swizzled (slot ^= row&7, inverse swizzle on global source —
// both-sides-or-neither). KW=3: conv as accumulating passes over shifted row
// windows, flattened into one (tap,kk) step loop. Epilogue: bias(+relu),
// transposed bf16 tile via LDS, optional fused row-norms. Optional FUSED
// second GEMM (conv3): B-operand straight from the epilogue LDS tile,
// A-operand (Wq3) from global/L2 — eliminates the Bmat5 round-trip and the
// third launch. Two independent GEMMs per launch (flat-grid split).
// ---------------------------------------------------------------------------
struct GArgs {
    const unsigned short* A;
    const unsigned short* Bm;
    const float* bias;
    unsigned short* Y;
    float* nrm;
    int Ck, N, Mpad, nx, relu, norm, Cout;
    const unsigned short* A2;   // fused: [128][128] bf16 weights (conv3)
    const float* bias2;         // fused: [100]
    unsigned short* Y2;         // fused: [b][N][128] output
    float* nrm2;                // fused: [b*N] row norms
    int fuse;
};

template<int KW>
__global__ __launch_bounds__(256) void gemm_pair(GArgs g0, GArgs g1, int n0)
{
    __shared__ __align__(16) unsigned char smem[67584];
    unsigned short* Al = (unsigned short*)smem;           // A0,B0,A1,B1 [128][64] each
    unsigned short* Ct = (unsigned short*)smem;           // [128][136] epilogue (alias)
    float* biasS  = (float*)(smem + 65536);               // [128]
    float* bias2S = (float*)(smem + 66048);               // [128]
    float* normS  = (float*)(smem + 66560);               // [2][128]

    const bool first = (blockIdx.x < (unsigned)n0);
    const GArgs g = first ? g0 : g1;
    const int idx = first ? blockIdx.x : (blockIdx.x - n0);
    const int ny = g.Mpad >> 7;
    const int per_b = g.nx * ny;
    const int b = idx / per_b; const int rem = idx - b * per_b;
    const int y = rem / g.nx, x = rem - y * g.nx;
    const int co0 = y * 128, t0 = x * 128;

    const int tid = threadIdx.x;
    const int wave = tid >> 6, lane = tid & 63;
    const int lm = lane & 15, kg = lane >> 4;
    const int mbase = (wave >> 1) * 64, nbase = (wave & 1) * 64;

    if (tid < 128) {
        biasS[tid] = (co0 + tid < g.Cout) ? g.bias[co0 + tid] : 0.f;
        if (g.fuse) bias2S[tid] = (tid < 100) ? g.bias2[tid] : 0.f;
    }

    // staging lane decomposition: 8 rows x 8 16B-slots per wave-call
    const int r7 = lane >> 3;            // relative row 0..7
    const int s7 = lane & 7;             // physical 16B slot 0..7
    const int swz = ((s7 ^ r7) * 8);     // inverse-swizzled global col (elems)
    const int Ck = g.Ck;
    const int ksteps = Ck >> 6;
    const int kshift = __builtin_ctz(ksteps);
    const int nsteps = KW * ksteps;

    auto stage = [&](int s) {
        const int dk = s >> kshift;
        const int kk = (s & (ksteps - 1)) << 6;
        const unsigned short* Ag = g.A + ((size_t)dk * g.Mpad + co0) * Ck + kk;
        const unsigned short* Bg = g.Bm +
            ((size_t)b * (g.N + (KW == 3 ? 2 : 0)) + t0 + dk) * Ck + kk;
        unsigned short* Ad = Al + (s & 1) * 16384;
        unsigned short* Bd = Ad + 8192;
#pragma unroll
        for (int i = 0; i < 4; ++i) {
            int R0 = wave * 32 + i * 8;   // wave-uniform LDS base row
            async16(Ag + (size_t)(R0 + r7) * Ck + swz, Ad + R0 * 64);
            async16(Bg + (size_t)(R0 + r7) * Ck + swz, Bd + R0 * 64);
        }
    };

    f32x4 acc[4][4];
#pragma unroll
    for (int mi = 0; mi < 4; ++mi)
#pragma unroll
        for (int ni = 0; ni < 4; ++ni) acc[mi][ni] = (f32x4){0.f, 0.f, 0.f, 0.f};

    stage(0);
    __syncthreads();
#pragma unroll 1
    for (int s = 0; s < nsteps; ++s) {
        if (s + 1 < nsteps) stage(s + 1);
        const unsigned short* Ab = Al + (s & 1) * 16384;
        const unsigned short* Bb = Ab + 8192;
#pragma unroll
        for (int kk2 = 0; kk2 < 2; ++kk2) {
            short8 av[4], bv[4];
#pragma unroll
            for (int mi = 0; mi < 4; ++mi) {
                int row = mbase + mi * 16 + lm;
                av[mi] = *(const short8*)(Ab + row * 64 +
                                          (((kk2 * 4 + kg) ^ (lm & 7)) * 8));
            }
#pragma unroll
            for (int ni = 0; ni < 4; ++ni) {
                int row = nbase + ni * 16 + lm;
                bv[ni] = *(const short8*)(Bb + row * 64 +
                                          (((kk2 * 4 + kg) ^ (lm & 7)) * 8));
            }
#pragma unroll
            for (int mi = 0; mi < 4; ++mi)
#pragma unroll
                for (int ni = 0; ni < 4; ++ni)
                    acc[mi][ni] = __builtin_amdgcn_mfma_f32_16x16x32_bf16(
                        av[mi], bv[ni], acc[mi][ni], 0, 0, 0);
        }
        __syncthreads();   // drains vmcnt(0): stage(s+1) landed; readers done
    }

    // epilogue: bias(+relu), stage transposed bf16 tile, optional row-norms
    auto epi = [&](f32x4 (&A)[4][4], const float* bS, int dorelu, int donorm) {
        float sq[4] = {0.f, 0.f, 0.f, 0.f};
#pragma unroll
        for (int mi = 0; mi < 4; ++mi)
#pragma unroll
            for (int ni = 0; ni < 4; ++ni)
#pragma unroll
                for (int r = 0; r < 4; ++r) {
                    int co_l = mbase + mi * 16 + kg * 4 + r;
                    int t_l  = nbase + ni * 16 + lm;
                    float v = A[mi][ni][r] + bS[co_l];
                    if (dorelu) v = fmaxf(v, 0.f);
                    Ct[t_l * 136 + co_l] = f2bf(v);
                    sq[ni] += v * v;
                }
        if (donorm) {
#pragma unroll
            for (int ni = 0; ni < 4; ++ni) {
                float s = sq[ni];
                s += __shfl_xor(s, 16, 64);
                s += __shfl_xor(s, 32, 64);
                if (kg == 0) normS[(wave >> 1) * 128 + nbase + ni * 16 + lm] = s;
            }
        }
    };

    if (!g.fuse) {
        epi(acc, biasS, g.relu, g.norm);
        __syncthreads();
        unsigned short* Yb = g.Y + ((size_t)b * g.N + t0) * g.Mpad + co0;
        int c0 = (tid & 15) * 8;
#pragma unroll
        for (int p = 0; p < 8; ++p) {
            int r = (tid >> 4) + p * 16;
            *(uint4*)(Yb + (size_t)r * g.Mpad + c0) = *(const uint4*)(Ct + r * 136 + c0);
        }
        if (g.norm && tid < 128)
            g.nrm[(size_t)b * g.N + t0 + tid] = normS[tid] + normS[128 + tid];
    } else {
        // first epilogue: relu(conv2) tile -> Ct [t][136]
        epi(acc, biasS, 1, 0);
        __syncthreads();
        // fused conv3 GEMM: A2 [128 m][128 k] from global (L2-hot), B from Ct
        f32x4 acc2[4][4];
#pragma unroll
        for (int mi = 0; mi < 4; ++mi)
#pragma unroll
            for (int ni = 0; ni < 4; ++ni) acc2[mi][ni] = (f32x4){0.f, 0.f, 0.f, 0.f};
#pragma unroll
        for (int kk = 0; kk < 128; kk += 32) {
            short8 av2[4], bv2[4];
#pragma unroll
            for (int mi = 0; mi < 4; ++mi)
                av2[mi] = *(const short8*)(g.A2 +
                    (size_t)(mbase + mi * 16 + lm) * 128 + kk + kg * 8);
#pragma unroll
            for (int ni = 0; ni < 4; ++ni)
                bv2[ni] = *(const short8*)(Ct +
                    (nbase + ni * 16 + lm) * 136 + kk + kg * 8);
#pragma unroll
            for (int mi = 0; mi < 4; ++mi)
#pragma unroll
                for (int ni = 0; ni < 4; ++ni)
                    acc2[mi][ni] = __builtin_amdgcn_mfma_f32_16x16x32_bf16(
                        av2[mi], bv2[ni], acc2[mi][ni], 0, 0, 0);
        }
        __syncthreads();   // all Ct reads done before rewrite
        epi(acc2, bias2S, 0, 1);
        __syncthreads();
        unsigned short* Yb = g.Y2 + ((size_t)b * g.N + t0) * 128 + co0;
        int c0 = (tid & 15) * 8;
#pragma unroll
        for (int p = 0; p < 8; ++p) {
            int r = (tid >> 4) + p * 16;
            *(uint4*)(Yb + (size_t)r * 128 + c0) = *(const uint4*)(Ct + r * 136 + c0);
        }
        if (tid < 128)
            g.nrm2[(size_t)b * g.N + t0 + tid] = normS[tid] + normS[128 + tid];
    }
}

// ---------------------------------------------------------------------------
// MFMA attention (unchanged — passed). Block = (b, 32 q-rows) x all 512 cols;
// wave w owns cols [128w,128w+128); frags straight from L2.
// ---------------------------------------------------------------------------
__global__ __launch_bounds__(256) void attn_mfma(
    const unsigned short* __restrict__ q,   // [B*T1][128] bf16
    const unsigned short* __restrict__ k,   // [B*T2][128] bf16
    const float* __restrict__ q2,           // [B*T1]
    const float* __restrict__ k2,           // [B*T2]
    const unsigned char* __restrict__ mask, // [B*T2]
    const float* __restrict__ prior,        // [B,T1,T2]
    float* __restrict__ out_attn, float* __restrict__ out_logp)
{
    __shared__ float redM[4][32], redS[4][32];
    __shared__ float rowA[32], rowB[32];

    const int b = blockIdx.y, t0 = blockIdx.x * 32;
    const int tid = threadIdx.x, wave = tid >> 6, lane = tid & 63;
    const int lm = lane & 15, quad = lane >> 4;
    const float NEG_INF = -__builtin_huge_valf();

    const unsigned short* qb = q + ((size_t)b * T1_ + t0) * 128;
    short8 af[2][4];
#pragma unroll
    for (int mi = 0; mi < 2; ++mi)
#pragma unroll
        for (int kb = 0; kb < 4; ++kb)
            af[mi][kb] = *(const short8*)(qb + (size_t)(mi * 16 + lm) * 128 + kb * 32 + quad * 8);

    f32x4 acc[2][8];
#pragma unroll
    for (int mi = 0; mi < 2; ++mi)
#pragma unroll
        for (int nf = 0; nf < 8; ++nf) acc[mi][nf] = (f32x4){0.f, 0.f, 0.f, 0.f};

    const unsigned short* kp = k + ((size_t)b * T2_ + wave * 128) * 128;
#pragma unroll
    for (int nf = 0; nf < 8; ++nf) {
        short8 bfr[4];
#pragma unroll
        for (int kb = 0; kb < 4; ++kb)
            bfr[kb] = *(const short8*)(kp + (size_t)(nf * 16 + lm) * 128 + kb * 32 + quad * 8);
#pragma unroll
        for (int mi = 0; mi < 2; ++mi)
#pragma unroll
            for (int kb = 0; kb < 4; ++kb)
                acc[mi][nf] = __builtin_amdgcn_mfma_f32_16x16x32_bf16(
                    af[mi][kb], bfr[kb], acc[mi][nf], 0, 0, 0);
    }

    float k2v[8];
    unsigned char mk[8];
#pragma unroll
    for (int nf = 0; nf < 8; ++nf) {
        int col = wave * 128 + nf * 16 + lm;
        k2v[nf] = k2[b * T2_ + col];
        mk[nf]  = mask[b * T2_ + col];
    }
    float q2v[2][4];
#pragma unroll
    for (int mi = 0; mi < 2; ++mi)
#pragma unroll
        for (int r = 0; r < 4; ++r)
            q2v[mi][r] = q2[b * T1_ + t0 + mi * 16 + quad * 4 + r];
#pragma unroll
    for (int mi = 0; mi < 2; ++mi)
#pragma unroll
        for (int nf = 0; nf < 8; ++nf)
#pragma unroll
            for (int r = 0; r < 4; ++r)
                acc[mi][nf][r] = 1e-3f * acc[mi][nf][r] - 5e-4f * (q2v[mi][r] + k2v[nf]);

#pragma unroll
    for (int mi = 0; mi < 2; ++mi)
#pragma unroll
        for (int r = 0; r < 4; ++r) {
            float m = NEG_INF;
#pragma unroll
            for (int nf = 0; nf < 8; ++nf) m = fmaxf(m, acc[mi][nf][r]);
#pragma unroll
            for (int d = 1; d <= 8; d <<= 1) m = fmaxf(m, __shfl_xor(m, d, 64));
            float s = 0.f;
#pragma unroll
            for (int nf = 0; nf < 8; ++nf) s += __expf(acc[mi][nf][r] - m);
#pragma unroll
            for (int d = 1; d <= 8; d <<= 1) s += __shfl_xor(s, d, 64);
            if (lm == 0) {
                redM[wave][mi * 16 + quad * 4 + r] = m;
                redS[wave][mi * 16 + quad * 4 + r] = s;
            }
        }
    __syncthreads();
    if (tid < 32) {
        float m = redM[0][tid];
        m = fmaxf(m, redM[1][tid]); m = fmaxf(m, redM[2][tid]); m = fmaxf(m, redM[3][tid]);
        float s = 0.f;
#pragma unroll
        for (int w = 0; w < 4; ++w) s += redS[w][tid] * __expf(redM[w][tid] - m);
        rowA[tid] = m + __logf(s);   // L1
    }
    __syncthreads();
    float L1[2][4];
#pragma unroll
    for (int mi = 0; mi < 2; ++mi)
#pragma unroll
        for (int r = 0; r < 4; ++r) L1[mi][r] = rowA[mi * 16 + quad * 4 + r];

    const size_t base = ((size_t)b * T1_ + t0) * T2_;
#pragma unroll
    for (int mi = 0; mi < 2; ++mi)
#pragma unroll
        for (int r = 0; r < 4; ++r) {
            size_t rowoff = base + (size_t)(mi * 16 + quad * 4 + r) * T2_;
#pragma unroll
            for (int nf = 0; nf < 8; ++nf) {
                int col = wave * 128 + nf * 16 + lm;
                float pv = prior[rowoff + col];
                float t = acc[mi][nf][r] + __logf(pv + 1e-8f);
                out_logp[rowoff + col] = t - L1[mi][r];
                acc[mi][nf][r] = mk[nf] ? NEG_INF : t;
            }
        }

#pragma unroll
    for (int mi = 0; mi < 2; ++mi)
#pragma unroll
        for (int r = 0; r < 4; ++r) {
            float m = NEG_INF;
#pragma unroll
            for (int nf = 0; nf < 8; ++nf) m = fmaxf(m, acc[mi][nf][r]);
#pragma unroll
            for (int d = 1; d <= 8; d <<= 1) m = fmaxf(m, __shfl_xor(m, d, 64));
            float s = 0.f;
#pragma unroll
            for (int nf = 0; nf < 8; ++nf) s += __expf(acc[mi][nf][r] - m);
#pragma unroll
            for (int d = 1; d <= 8; d <<= 1) s += __shfl_xor(s, d, 64);
            if (lm == 0) {
                redM[wave][mi * 16 + quad * 4 + r] = m;
                redS[wave][mi * 16 + quad * 4 + r] = s;
            }
        }
    __syncthreads();
    if (tid < 32) {
        float m = redM[0][tid];
        m = fmaxf(m, redM[1][tid]); m = fmaxf(m, redM[2][tid]); m = fmaxf(m, redM[3][tid]);
        float s = 0.f;
#pragma unroll
        for (int w = 0; w < 4; ++w) s += redS[w][tid] * __expf(redM[w][tid] - m);
        rowA[tid] = m;
        rowB[tid] = 1.0f / s;
    }
    __syncthreads();

#pragma unroll
    for (int mi = 0; mi < 2; ++mi)
#pragma unroll
        for (int r = 0; r < 4; ++r) {
            int rl = mi * 16 + quad * 4 + r;
            float m2 = rowA[rl], is2 = rowB[rl];
            size_t rowoff = base + (size_t)rl * T2_;
#pragma unroll
            for (int nf = 0; nf < 8; ++nf) {
                int col = wave * 128 + nf * 16 + lm;
                out_attn[rowoff + col] = __expf(acc[mi][nf][r] - m2) * is2;
            }
        }
}

extern "C" void kernel_launch(void* const* d_in, const int* in_sizes, int n_in,
                              void* d_out, int out_size, void* d_ws, size_t ws_size,
                              hipStream_t stream)
{
    const float* queries = (const float*)d_in[0];
    const float* keys    = (const float*)d_in[1];
    const unsigned char* mask = (const unsigned char*)d_in[3];
    const float* prior   = (const float*)d_in[4];
    const float* kW1 = (const float*)d_in[5];
    const float* kb1 = (const float*)d_in[6];
    const float* kW2 = (const float*)d_in[7];
    const float* kb2 = (const float*)d_in[8];
    const float* qW1 = (const float*)d_in[9];
    const float* qb1 = (const float*)d_in[10];
    const float* qW2 = (const float*)d_in[11];
    const float* qb2 = (const float*)d_in[12];
    const float* qW3 = (const float*)d_in[13];
    const float* qb3 = (const float*)d_in[14];

    // workspace (ushort units):
    unsigned short* ws = (unsigned short*)d_ws;
    unsigned short* keysT    = ws;                       //  32*514*512  = 8,421,376
    unsigned short* queriesT = ws + 8421376;             //  32*2050*128 = 8,396,800
    unsigned short* Bmat2    = ws + 16818176;            //  [32][512][1024]
    unsigned short* Bmat4    = ws + 33595392;            //  [32][2048][256]
    unsigned short* q_att    = ws + 58761216;            //  [32][2048][128]
    unsigned short* k_att    = ws + 67149824;            //  [32][512][128]
    unsigned short* Wdst     = ws + 69246976;            //  1,851,392 (5 regions)
    unsigned short* Wk1s = Wdst;                         //  [3][1024][512]
    unsigned short* Wk2  = Wdst + 1572864;               //  [128][1024]
    unsigned short* Wq1s = Wdst + 1703936;               //  [3][256][128]
    unsigned short* Wq2  = Wdst + 1802240;               //  [128][256]
    unsigned short* Wq3  = Wdst + 1835008;               //  [128][128]
    float* q2f = (float*)(ws + 71098368);                //  [65536] f32
    float* k2f = q2f + 65536;                            //  [16384] f32

    float* out_attn = (float*)d_out;
    float* out_logp = (float*)d_out + (size_t)B_ * T1_ * T2_;

    dim3 blk(256);
    prep_kernel<<<dim3(5120), blk, 0, stream>>>(queries, keys, kW1, kW2, qW1, qW2, qW3,
                                                keysT, queriesT, Wdst);

    GArgs a_key1 = {Wk1s, keysT,    kb1, Bmat2, nullptr, 512,  512, 1024,  4, 1, 0, 1024,
                    nullptr, nullptr, nullptr, nullptr, 0};
    GArgs a_q1   = {Wq1s, queriesT, qb1, Bmat4, nullptr, 128, 2048,  256, 16, 1, 0,  200,
                    nullptr, nullptr, nullptr, nullptr, 0};
    gemm_pair<3><<<dim3(2048), blk, 0, stream>>>(a_key1, a_q1, 1024);

    GArgs a_key2 = {Wk2, Bmat2, kb2, k_att, k2f,     1024,  512, 128,  4, 0, 1, 100,
                    nullptr, nullptr, nullptr, nullptr, 0};
    GArgs a_q23  = {Wq2, Bmat4, qb2, nullptr, nullptr, 256, 2048, 128, 16, 1, 0, 100,
                    Wq3, qb3, q_att, q2f, 1};
    gemm_pair<1><<<dim3(640), blk, 0, stream>>>(a_key2, a_q23, 128);

    attn_mfma<<<dim3(T1_ / 32, B_), blk, 0, stream>>>(q_att, k_att, q2f, k2f, mask, prior,
                                                      out_attn, out_logp);

    (void)in_sizes; (void)n_in; (void)out_size; (void)ws_size;
}